// Round 1
// baseline (244.773 us; speedup 1.0000x reference)
//
#include <hip/hip_runtime.h>

#define N_NODES 10000
#define N_EDGES 160000
#define NC 8
#define NB 64
#define LN_EPS 1e-5f

// ---------------- K1: transpose x (B,E) -> xT (E,B) ----------------
__global__ void transpose_x_kernel(const float* __restrict__ x, float* __restrict__ xT) {
  __shared__ float tile[64][65];
  const int e0 = blockIdx.x * 64;
  const int tx = threadIdx.x & 63;   // e within tile on load, also e on store
  const int ty = threadIdx.x >> 6;   // 0..3
#pragma unroll
  for (int j = 0; j < 16; ++j) {
    const int b = j * 4 + ty;
    tile[tx][b] = x[(size_t)b * N_EDGES + e0 + tx];
  }
  __syncthreads();
#pragma unroll
  for (int j = 0; j < 16; ++j) {
    const int r = j * 4 + ty;
    xT[(size_t)(e0 + r) * 64 + tx] = tile[r][tx];
  }
}

// ---------------- K2: histogram of dst and src ----------------
__global__ void hist_kernel(const int* __restrict__ edst, const int* __restrict__ esrc,
                            int* __restrict__ cnt_dst, int* __restrict__ cnt_src) {
  const int e = blockIdx.x * 256 + threadIdx.x;
  if (e < N_EDGES) {
    atomicAdd(&cnt_dst[edst[e]], 1);
    atomicAdd(&cnt_src[esrc[e]], 1);
  }
}

// ---------------- K3: exclusive scan (two blocks: dst, src) ----------------
__global__ void scan_kernel(const int* __restrict__ cnt_dst, const int* __restrict__ cnt_src,
                            int* __restrict__ start_dst, int* __restrict__ cur_dst,
                            int* __restrict__ start_src, int* __restrict__ cur_src) {
  const int* cnt = blockIdx.x ? cnt_src : cnt_dst;
  int* start = blockIdx.x ? start_src : start_dst;
  int* cur   = blockIdx.x ? cur_src   : cur_dst;

  __shared__ int part[256];
  const int t = threadIdx.x;
  const int lo = t * 40;
  const int hi = min(lo + 40, N_NODES);
  int s = 0;
  for (int i = lo; i < hi; ++i) s += cnt[i];
  part[t] = s;
  __syncthreads();
  // inclusive Hillis-Steele scan
  for (int d = 1; d < 256; d <<= 1) {
    int v = (t >= d) ? part[t - d] : 0;
    __syncthreads();
    part[t] += v;
    __syncthreads();
  }
  int base = (t == 0) ? 0 : part[t - 1];
  for (int i = lo; i < hi; ++i) {
    start[i] = base;
    cur[i] = base;
    base += cnt[i];
  }
  if (t == 255) start[N_NODES] = base;   // == N_EDGES
}

// ---------------- K4: scatter edge ids into sorted order ----------------
__global__ void scatter_kernel(const int* __restrict__ edst, const int* __restrict__ esrc,
                               int* __restrict__ cur_dst, int* __restrict__ cur_src,
                               int* __restrict__ sorted_dst, int* __restrict__ sorted_src) {
  const int e = blockIdx.x * 256 + threadIdx.x;
  if (e < N_EDGES) {
    int p = atomicAdd(&cur_dst[edst[e]], 1);
    sorted_dst[p] = e;
    int q = atomicAdd(&cur_src[esrc[e]], 1);
    sorted_src[q] = e;
  }
}

// ---------------- K5: fused segment-sum + LN + ELU + src-side dot ----------------
// 256 threads = 4 nodes per block, lane b = batch index. h never hits memory.
__global__ void __launch_bounds__(256) node_kernel(
    const float* __restrict__ xT, const float* __restrict__ w1,
    const float* __restrict__ b1, const float* __restrict__ gamma,
    const float* __restrict__ beta, const float* __restrict__ w3,
    const int* __restrict__ sorted_dst, const int* __restrict__ start_dst,
    const int* __restrict__ sorted_src, const int* __restrict__ start_src,
    float* __restrict__ outT) {
  const int n = blockIdx.x * 4 + (threadIdx.x >> 6);
  const int b = threadIdx.x & 63;
  if (n >= N_NODES) return;

  float a[NC];
#pragma unroll
  for (int c = 0; c < NC; ++c) a[c] = 0.f;

  const int s0 = start_dst[n];
  const int s1 = start_dst[n + 1];
  for (int i = s0; i < s1; ++i) {
    const int e = sorted_dst[i];                       // wave-uniform (scalar)
    const float xe = xT[(size_t)e * 64 + b];           // coalesced 256B
    const float4* wp = (const float4*)(w1 + (size_t)e * NC);  // broadcast
    const float4 wa = wp[0], wb = wp[1];
    a[0] += xe * wa.x; a[1] += xe * wa.y; a[2] += xe * wa.z; a[3] += xe * wa.w;
    a[4] += xe * wb.x; a[5] += xe * wb.y; a[6] += xe * wb.z; a[7] += xe * wb.w;
  }

  // + b1, LayerNorm over C (all in registers), gamma/beta, ELU
  const float4* b1p = (const float4*)(b1 + (size_t)n * NC);
  const float4 b1a = b1p[0], b1b = b1p[1];
  a[0] += b1a.x; a[1] += b1a.y; a[2] += b1a.z; a[3] += b1a.w;
  a[4] += b1b.x; a[5] += b1b.y; a[6] += b1b.z; a[7] += b1b.w;

  float mu = 0.f;
#pragma unroll
  for (int c = 0; c < NC; ++c) mu += a[c];
  mu *= 0.125f;
  float var = 0.f;
#pragma unroll
  for (int c = 0; c < NC; ++c) { a[c] -= mu; var += a[c] * a[c]; }
  var *= 0.125f;
  const float rs = rsqrtf(var + LN_EPS);

  const float4* gp = (const float4*)(gamma + (size_t)n * NC);
  const float4 ga = gp[0], gb = gp[1];
  const float4* bp = (const float4*)(beta + (size_t)n * NC);
  const float4 ba = bp[0], bb = bp[1];
  float v[NC];
  v[0] = a[0] * rs * ga.x + ba.x;  v[1] = a[1] * rs * ga.y + ba.y;
  v[2] = a[2] * rs * ga.z + ba.z;  v[3] = a[3] * rs * ga.w + ba.w;
  v[4] = a[4] * rs * gb.x + bb.x;  v[5] = a[5] * rs * gb.y + bb.y;
  v[6] = a[6] * rs * gb.z + bb.z;  v[7] = a[7] * rs * gb.w + bb.w;
#pragma unroll
  for (int c = 0; c < NC; ++c) v[c] = v[c] > 0.f ? v[c] : expm1f(v[c]);

  // src-side: for every edge whose src == n, write outT[e][b] = <v, w3[e]>
  const int t0 = start_src[n];
  const int t1 = start_src[n + 1];
  for (int i = t0; i < t1; ++i) {
    const int e = sorted_src[i];                       // wave-uniform
    const float4* wp = (const float4*)(w3 + (size_t)e * NC);  // broadcast
    const float4 wa = wp[0], wb = wp[1];
    const float dot = v[0] * wa.x + v[1] * wa.y + v[2] * wa.z + v[3] * wa.w +
                      v[4] * wb.x + v[5] * wb.y + v[6] * wb.z + v[7] * wb.w;
    outT[(size_t)e * 64 + b] = dot;                    // coalesced 256B
  }
}

// ---------------- K6: transpose outT (E,B) -> out (B,E), + b3 + x ----------------
__global__ void finalize_kernel(const float* __restrict__ outT, const float* __restrict__ b3,
                                const float* __restrict__ x, float* __restrict__ out) {
  __shared__ float tile[64][65];
  const int e0 = blockIdx.x * 64;
  const int tx = threadIdx.x & 63;
  const int ty = threadIdx.x >> 6;
#pragma unroll
  for (int j = 0; j < 16; ++j) {
    const int r = j * 4 + ty;
    tile[r][tx] = outT[(size_t)(e0 + r) * 64 + tx];    // coalesced read
  }
  __syncthreads();
  const float bb = b3[e0 + tx];
#pragma unroll
  for (int j = 0; j < 16; ++j) {
    const int b = j * 4 + ty;
    out[(size_t)b * N_EDGES + e0 + tx] =
        tile[tx][b] + bb + x[(size_t)b * N_EDGES + e0 + tx];  // coalesced
  }
}

extern "C" void kernel_launch(void* const* d_in, const int* in_sizes, int n_in,
                              void* d_out, int out_size, void* d_ws, size_t ws_size,
                              hipStream_t stream) {
  const float* x     = (const float*)d_in[0];
  const float* w1    = (const float*)d_in[1];
  const float* b1    = (const float*)d_in[2];
  const float* gamma = (const float*)d_in[3];
  const float* beta  = (const float*)d_in[4];
  const float* w3    = (const float*)d_in[5];
  const float* b3    = (const float*)d_in[6];
  const int* esrc    = (const int*)d_in[7];
  const int* edst    = (const int*)d_in[8];
  float* out = (float*)d_out;

  char* ws = (char*)d_ws;
  size_t off = 0;
  auto alloc = [&](size_t bytes) -> void* {
    void* p = ws + off;
    off += (bytes + 255) & ~(size_t)255;
    return p;
  };
  float* xT        = (float*)alloc((size_t)N_EDGES * NB * 4);
  float* outT      = (float*)alloc((size_t)N_EDGES * NB * 4);
  int* cnt_dst     = (int*)alloc((size_t)N_NODES * 4);
  int* cnt_src     = (int*)alloc((size_t)N_NODES * 4);
  int* start_dst   = (int*)alloc((size_t)(N_NODES + 1) * 4);
  int* start_src   = (int*)alloc((size_t)(N_NODES + 1) * 4);
  int* cur_dst     = (int*)alloc((size_t)N_NODES * 4);
  int* cur_src     = (int*)alloc((size_t)N_NODES * 4);
  int* sorted_dst  = (int*)alloc((size_t)N_EDGES * 4);
  int* sorted_src  = (int*)alloc((size_t)N_EDGES * 4);

  // zero both histograms (ws is re-poisoned before every launch)
  hipMemsetAsync(cnt_dst, 0, (size_t)2 * N_NODES * 4 + 512, stream);

  transpose_x_kernel<<<N_EDGES / 64, 256, 0, stream>>>(x, xT);
  hist_kernel<<<N_EDGES / 256, 256, 0, stream>>>(edst, esrc, cnt_dst, cnt_src);
  scan_kernel<<<2, 256, 0, stream>>>(cnt_dst, cnt_src, start_dst, cur_dst, start_src, cur_src);
  scatter_kernel<<<N_EDGES / 256, 256, 0, stream>>>(edst, esrc, cur_dst, cur_src,
                                                    sorted_dst, sorted_src);
  node_kernel<<<N_NODES / 4, 256, 0, stream>>>(xT, w1, b1, gamma, beta, w3,
                                               sorted_dst, start_dst,
                                               sorted_src, start_src, outT);
  finalize_kernel<<<N_EDGES / 64, 256, 0, stream>>>(outT, b3, x, out);
}

// Round 2
// 210.671 us; speedup vs baseline: 1.1619x; 1.1619x over previous
//
#include <hip/hip_runtime.h>

#define N_NODES 10000
#define N_EDGES 160000
#define NC 8
#define NB 64
#define LN_EPS 1e-5f

// ---------------- K1: transpose x (B,E) -> xT (E,B), fused edge histograms ----
__global__ void __launch_bounds__(256) transpose_x_kernel(
    const float* __restrict__ x, float* __restrict__ xT,
    const int* __restrict__ edst, const int* __restrict__ esrc,
    int* __restrict__ cnt_dst, int* __restrict__ cnt_src) {
  __shared__ float tile[64][68];          // tile[e][b], padded for b128 reads
  const int e0 = blockIdx.x * 64;
  const int t = threadIdx.x;
  if (t < 64) {                           // fused histogram (this block's edges)
    atomicAdd(&cnt_dst[edst[e0 + t]], 1);
    atomicAdd(&cnt_src[esrc[e0 + t]], 1);
  }
  const int u = t & 15;                   // group of 4 inner elements
  const int row = t >> 4;                 // 0..15
#pragma unroll
  for (int j = 0; j < 4; ++j) {           // read x rows (b), float4 over e
    const int b = j * 16 + row;
    const float4 v = *(const float4*)&x[(size_t)b * N_EDGES + e0 + 4 * u];
    tile[4 * u + 0][b] = v.x; tile[4 * u + 1][b] = v.y;
    tile[4 * u + 2][b] = v.z; tile[4 * u + 3][b] = v.w;
  }
  __syncthreads();
#pragma unroll
  for (int j = 0; j < 4; ++j) {           // write xT rows (e), float4 over b
    const int e = j * 16 + row;
    const float4 v = *(const float4*)&tile[e][4 * u];
    *(float4*)&xT[(size_t)(e0 + e) * 64 + 4 * u] = v;
  }
}

// ---------------- K2: exclusive scan (two blocks: dst, src) ----------------
__global__ void __launch_bounds__(1024) scan_kernel(
    const int* __restrict__ cnt_dst, const int* __restrict__ cnt_src,
    int* __restrict__ start_dst, int* __restrict__ cur_dst,
    int* __restrict__ start_src, int* __restrict__ cur_src) {
  const int* cnt = blockIdx.x ? cnt_src : cnt_dst;
  int* start = blockIdx.x ? start_src : start_dst;
  int* cur   = blockIdx.x ? cur_src   : cur_dst;

  const int t = threadIdx.x;
  const int lane = t & 63;
  const int wid = t >> 6;                 // 0..15
  const int lo = t * 10;
  const int hi = min(lo + 10, N_NODES);
  int s = 0;
  for (int i = lo; i < hi; ++i) s += cnt[i];
  const int own = s;
  // inclusive scan within wave (shfl_up)
#pragma unroll
  for (int d = 1; d < 64; d <<= 1) {
    const int v = __shfl_up(s, d, 64);
    if (lane >= d) s += v;
  }
  __shared__ int wsum[16];
  if (lane == 63) wsum[wid] = s;
  __syncthreads();
  if (t == 0) {
    int acc = 0;
#pragma unroll
    for (int i = 0; i < 16; ++i) { acc += wsum[i]; wsum[i] = acc; }
  }
  __syncthreads();
  int base = (wid ? wsum[wid - 1] : 0) + s - own;   // exclusive start for this thread
  for (int i = lo; i < hi; ++i) {
    start[i] = base;
    cur[i] = base;
    base += cnt[i];
  }
  if (t == 1023) start[N_NODES] = base;   // == N_EDGES
}

// ---------------- K3: scatter edge ids into sorted order ----------------
__global__ void scatter_kernel(const int* __restrict__ edst, const int* __restrict__ esrc,
                               int* __restrict__ cur_dst, int* __restrict__ cur_src,
                               int* __restrict__ sorted_dst, int* __restrict__ sorted_src) {
  const int e = blockIdx.x * 256 + threadIdx.x;
  if (e < N_EDGES) {
    const int p = atomicAdd(&cur_dst[edst[e]], 1);
    sorted_dst[p] = e;
    const int q = atomicAdd(&cur_src[esrc[e]], 1);
    sorted_src[q] = e;
  }
}

// ---------------- K4: fused segment-sum + LN + ELU + src-side dot ----------------
// 256 threads = 4 nodes per block, lane b = batch index. h never hits memory.
__global__ void __launch_bounds__(256) node_kernel(
    const float* __restrict__ xT, const float* __restrict__ w1,
    const float* __restrict__ b1, const float* __restrict__ gamma,
    const float* __restrict__ beta, const float* __restrict__ w3,
    const int* __restrict__ sorted_dst, const int* __restrict__ start_dst,
    const int* __restrict__ sorted_src, const int* __restrict__ start_src,
    float* __restrict__ outT) {
  const int n = blockIdx.x * 4 + (threadIdx.x >> 6);
  const int b = threadIdx.x & 63;

  float a[NC];
#pragma unroll
  for (int c = 0; c < NC; ++c) a[c] = 0.f;

  const int s0 = start_dst[n];
  const int s1 = start_dst[n + 1];
  int i = s0;
  // unrolled x4: batch index loads, then data loads -> 12 loads in flight
  for (; i + 4 <= s1; i += 4) {
    int ee[4];
#pragma unroll
    for (int k = 0; k < 4; ++k) ee[k] = sorted_dst[i + k];
    float xe[4];
#pragma unroll
    for (int k = 0; k < 4; ++k) xe[k] = xT[(size_t)ee[k] * 64 + b];
    float4 wla[4], wlb[4];
#pragma unroll
    for (int k = 0; k < 4; ++k) {
      const float4* wp = (const float4*)(w1 + (size_t)ee[k] * NC);
      wla[k] = wp[0]; wlb[k] = wp[1];
    }
#pragma unroll
    for (int k = 0; k < 4; ++k) {
      a[0] += xe[k] * wla[k].x; a[1] += xe[k] * wla[k].y;
      a[2] += xe[k] * wla[k].z; a[3] += xe[k] * wla[k].w;
      a[4] += xe[k] * wlb[k].x; a[5] += xe[k] * wlb[k].y;
      a[6] += xe[k] * wlb[k].z; a[7] += xe[k] * wlb[k].w;
    }
  }
  for (; i < s1; ++i) {
    const int e = sorted_dst[i];
    const float xe = xT[(size_t)e * 64 + b];
    const float4* wp = (const float4*)(w1 + (size_t)e * NC);
    const float4 wa = wp[0], wb = wp[1];
    a[0] += xe * wa.x; a[1] += xe * wa.y; a[2] += xe * wa.z; a[3] += xe * wa.w;
    a[4] += xe * wb.x; a[5] += xe * wb.y; a[6] += xe * wb.z; a[7] += xe * wb.w;
  }

  // + b1, LayerNorm over C (in registers), gamma/beta, ELU
  const float4* b1p = (const float4*)(b1 + (size_t)n * NC);
  const float4 b1a = b1p[0], b1b = b1p[1];
  a[0] += b1a.x; a[1] += b1a.y; a[2] += b1a.z; a[3] += b1a.w;
  a[4] += b1b.x; a[5] += b1b.y; a[6] += b1b.z; a[7] += b1b.w;

  float mu = 0.f;
#pragma unroll
  for (int c = 0; c < NC; ++c) mu += a[c];
  mu *= 0.125f;
  float var = 0.f;
#pragma unroll
  for (int c = 0; c < NC; ++c) { a[c] -= mu; var += a[c] * a[c]; }
  var *= 0.125f;
  const float rs = rsqrtf(var + LN_EPS);

  const float4* gp = (const float4*)(gamma + (size_t)n * NC);
  const float4 ga = gp[0], gb = gp[1];
  const float4* bp = (const float4*)(beta + (size_t)n * NC);
  const float4 ba = bp[0], bb = bp[1];
  float v[NC];
  v[0] = a[0] * rs * ga.x + ba.x;  v[1] = a[1] * rs * ga.y + ba.y;
  v[2] = a[2] * rs * ga.z + ba.z;  v[3] = a[3] * rs * ga.w + ba.w;
  v[4] = a[4] * rs * gb.x + bb.x;  v[5] = a[5] * rs * gb.y + bb.y;
  v[6] = a[6] * rs * gb.z + bb.z;  v[7] = a[7] * rs * gb.w + bb.w;
#pragma unroll
  for (int c = 0; c < NC; ++c) v[c] = v[c] > 0.f ? v[c] : expm1f(v[c]);

  // src-side: for every edge whose src == n, write outT[e][b] = <v, w3[e]>
  const int t0 = start_src[n];
  const int t1 = start_src[n + 1];
  int j = t0;
  for (; j + 4 <= t1; j += 4) {
    int ee[4];
#pragma unroll
    for (int k = 0; k < 4; ++k) ee[k] = sorted_src[j + k];
    float4 wla[4], wlb[4];
#pragma unroll
    for (int k = 0; k < 4; ++k) {
      const float4* wp = (const float4*)(w3 + (size_t)ee[k] * NC);
      wla[k] = wp[0]; wlb[k] = wp[1];
    }
#pragma unroll
    for (int k = 0; k < 4; ++k) {
      const float dot = v[0] * wla[k].x + v[1] * wla[k].y + v[2] * wla[k].z + v[3] * wla[k].w +
                        v[4] * wlb[k].x + v[5] * wlb[k].y + v[6] * wlb[k].z + v[7] * wlb[k].w;
      outT[(size_t)ee[k] * 64 + b] = dot;
    }
  }
  for (; j < t1; ++j) {
    const int e = sorted_src[j];
    const float4* wp = (const float4*)(w3 + (size_t)e * NC);
    const float4 wa = wp[0], wb = wp[1];
    const float dot = v[0] * wa.x + v[1] * wa.y + v[2] * wa.z + v[3] * wa.w +
                      v[4] * wb.x + v[5] * wb.y + v[6] * wb.z + v[7] * wb.w;
    outT[(size_t)e * 64 + b] = dot;
  }
}

// ---------------- K5: transpose outT (E,B) -> out (B,E), + b3 + x ----------------
__global__ void __launch_bounds__(256) finalize_kernel(
    const float* __restrict__ outT, const float* __restrict__ b3,
    const float* __restrict__ x, float* __restrict__ out) {
  __shared__ float tile[64][68];          // tile[b][e]
  const int e0 = blockIdx.x * 64;
  const int t = threadIdx.x;
  const int u = t & 15;
  const int row = t >> 4;
#pragma unroll
  for (int j = 0; j < 4; ++j) {           // read outT rows (e), float4 over b
    const int e = j * 16 + row;
    const float4 v = *(const float4*)&outT[(size_t)(e0 + e) * 64 + 4 * u];
    tile[4 * u + 0][e] = v.x; tile[4 * u + 1][e] = v.y;
    tile[4 * u + 2][e] = v.z; tile[4 * u + 3][e] = v.w;
  }
  __syncthreads();
  const float4 bb = *(const float4*)&b3[e0 + 4 * u];
#pragma unroll
  for (int j = 0; j < 4; ++j) {           // write out rows (b), float4 over e
    const int b = j * 16 + row;
    const float4 v = *(const float4*)&tile[b][4 * u];
    const float4 xb = *(const float4*)&x[(size_t)b * N_EDGES + e0 + 4 * u];
    float4 o;
    o.x = v.x + bb.x + xb.x;  o.y = v.y + bb.y + xb.y;
    o.z = v.z + bb.z + xb.z;  o.w = v.w + bb.w + xb.w;
    *(float4*)&out[(size_t)b * N_EDGES + e0 + 4 * u] = o;
  }
}

extern "C" void kernel_launch(void* const* d_in, const int* in_sizes, int n_in,
                              void* d_out, int out_size, void* d_ws, size_t ws_size,
                              hipStream_t stream) {
  const float* x     = (const float*)d_in[0];
  const float* w1    = (const float*)d_in[1];
  const float* b1    = (const float*)d_in[2];
  const float* gamma = (const float*)d_in[3];
  const float* beta  = (const float*)d_in[4];
  const float* w3    = (const float*)d_in[5];
  const float* b3    = (const float*)d_in[6];
  const int* esrc    = (const int*)d_in[7];
  const int* edst    = (const int*)d_in[8];
  float* out = (float*)d_out;

  char* ws = (char*)d_ws;
  size_t off = 0;
  auto alloc = [&](size_t bytes) -> void* {
    void* p = ws + off;
    off += (bytes + 255) & ~(size_t)255;
    return p;
  };
  float* xT        = (float*)alloc((size_t)N_EDGES * NB * 4);
  float* outT      = (float*)alloc((size_t)N_EDGES * NB * 4);
  int* cnt_dst     = (int*)alloc((size_t)N_NODES * 4);
  int* cnt_src     = (int*)alloc((size_t)N_NODES * 4);
  int* start_dst   = (int*)alloc((size_t)(N_NODES + 1) * 4);
  int* start_src   = (int*)alloc((size_t)(N_NODES + 1) * 4);
  int* cur_dst     = (int*)alloc((size_t)N_NODES * 4);
  int* cur_src     = (int*)alloc((size_t)N_NODES * 4);
  int* sorted_dst  = (int*)alloc((size_t)N_EDGES * 4);
  int* sorted_src  = (int*)alloc((size_t)N_EDGES * 4);

  // zero both histograms (ws is re-poisoned to 0xAA before every launch)
  hipMemsetAsync(cnt_dst, 0, (size_t)2 * N_NODES * 4 + 512, stream);

  transpose_x_kernel<<<N_EDGES / 64, 256, 0, stream>>>(x, xT, edst, esrc, cnt_dst, cnt_src);
  scan_kernel<<<2, 1024, 0, stream>>>(cnt_dst, cnt_src, start_dst, cur_dst, start_src, cur_src);
  scatter_kernel<<<N_EDGES / 256, 256, 0, stream>>>(edst, esrc, cur_dst, cur_src,
                                                    sorted_dst, sorted_src);
  node_kernel<<<N_NODES / 4, 256, 0, stream>>>(xT, w1, b1, gamma, beta, w3,
                                               sorted_dst, start_dst,
                                               sorted_src, start_src, outT);
  finalize_kernel<<<N_EDGES / 64, 256, 0, stream>>>(outT, b3, x, out);
}